// Round 1
// baseline (1165.961 us; speedup 1.0000x reference)
//
#include <hip/hip_runtime.h>

#define N_NODES 100000
#define N_EDGES 3200000
#define NFEAT 512
#define NHID 256
#define NCLASS 64
#define FCAT 128  // 2*NCLASS

// ---------------------------------------------------------------------------
// Weight prep: Wcat[k][j] = sum_m W1[k][m] * (j<64 ? W2 : Wres)[m][j&63]
// ---------------------------------------------------------------------------
__global__ void k_prep_wcat(const float* __restrict__ W1, const float* __restrict__ W2,
                            const float* __restrict__ Wres, float* __restrict__ Wcat) {
    int k = blockIdx.x;        // 0..511
    int j = threadIdx.x;       // 0..127
    const float* wb = (j < NCLASS) ? W2 : Wres;
    int jj = j & (NCLASS - 1);
    const float* w1row = W1 + (size_t)k * NHID;
    float acc = 0.f;
    for (int m = 0; m < NHID; ++m)
        acc += w1row[m] * wb[(size_t)m * NCLASS + jj];
    Wcat[(size_t)k * FCAT + j] = acc;
}

// c2[j] = b1 @ W2 ; cr[j] = b1 @ Wres + bres
__global__ void k_prep_c(const float* __restrict__ b1, const float* __restrict__ W2,
                         const float* __restrict__ Wres, const float* __restrict__ bres,
                         float* __restrict__ c2, float* __restrict__ cr) {
    int j = threadIdx.x;  // 0..127
    const float* wb = (j < NCLASS) ? W2 : Wres;
    int jj = j & (NCLASS - 1);
    float acc = 0.f;
    for (int m = 0; m < NHID; ++m)
        acc += b1[m] * wb[(size_t)m * NCLASS + jj];
    if (j < NCLASS) c2[jj] = acc;
    else            cr[jj] = acc + bres[jj];
}

// ---------------------------------------------------------------------------
// GEMM: A[N,128] = X[N,512] @ Wcat[512,128]   (f32 vector, tiled)
// block: 256 threads; tile BM=64 x BN=128, BK=64; thread computes 8x4 outputs
// ---------------------------------------------------------------------------
#define BM 64
#define BN 128
#define BK 64
__global__ __launch_bounds__(256) void k_gemm_a(const float* __restrict__ X,
                                                const float* __restrict__ Wcat,
                                                float* __restrict__ A) {
    __shared__ float xs[BM][BK];  // 16 KB
    __shared__ float ws[BK][BN];  // 32 KB
    int tid = threadIdx.x;
    int tx = tid & 31;   // N dir: 32 threads * 4 cols
    int ty = tid >> 5;   // M dir: 8 threads * 8 rows
    int row0 = blockIdx.x * BM;
    float acc[8][4] = {};

    for (int k0 = 0; k0 < NFEAT; k0 += BK) {
        // load X tile: 64x64 = 1024 float4
        for (int s = tid; s < (BM * BK) / 4; s += 256) {
            int r = s / (BK / 4);
            int c4 = s % (BK / 4);
            int gr = row0 + r;
            float4 v = make_float4(0.f, 0.f, 0.f, 0.f);
            if (gr < N_NODES)
                v = *(const float4*)(X + (size_t)gr * NFEAT + k0 + c4 * 4);
            *(float4*)(&xs[r][c4 * 4]) = v;
        }
        // load W tile: 64x128 = 2048 float4
        for (int s = tid; s < (BK * BN) / 4; s += 256) {
            int r = s / (BN / 4);
            int c4 = s % (BN / 4);
            *(float4*)(&ws[r][c4 * 4]) =
                *(const float4*)(Wcat + (size_t)(k0 + r) * FCAT + c4 * 4);
        }
        __syncthreads();

        for (int kk = 0; kk < BK; ++kk) {
            float xr[8];
#pragma unroll
            for (int m = 0; m < 8; ++m) xr[m] = xs[ty * 8 + m][kk];
            float4 wv = *(float4*)(&ws[kk][tx * 4]);
#pragma unroll
            for (int m = 0; m < 8; ++m) {
                acc[m][0] += xr[m] * wv.x;
                acc[m][1] += xr[m] * wv.y;
                acc[m][2] += xr[m] * wv.z;
                acc[m][3] += xr[m] * wv.w;
            }
        }
        __syncthreads();
    }
#pragma unroll
    for (int m = 0; m < 8; ++m) {
        int gr = row0 + ty * 8 + m;
        if (gr < N_NODES)
            *(float4*)(A + (size_t)gr * FCAT + tx * 4) =
                make_float4(acc[m][0], acc[m][1], acc[m][2], acc[m][3]);
    }
}

// ---------------------------------------------------------------------------
// CSR build
// ---------------------------------------------------------------------------
__global__ void k_hist(const int* __restrict__ rows, int* __restrict__ deg) {
    int e = blockIdx.x * 256 + threadIdx.x;
    if (e < N_EDGES) atomicAdd(&deg[rows[e]], 1);
}

__global__ void k_blocksums(const int* __restrict__ deg, int* __restrict__ blksum) {
    __shared__ int sh[256];
    int i = blockIdx.x * 256 + threadIdx.x;
    sh[threadIdx.x] = (i < N_NODES) ? deg[i] : 0;
    __syncthreads();
    for (int off = 128; off > 0; off >>= 1) {
        if (threadIdx.x < off) sh[threadIdx.x] += sh[threadIdx.x + off];
        __syncthreads();
    }
    if (threadIdx.x == 0) blksum[blockIdx.x] = sh[0];
}

__global__ void k_scan_blk(const int* __restrict__ blksum, int* __restrict__ blkofs,
                           int nblk, int* __restrict__ row_ofs) {
    if (threadIdx.x == 0 && blockIdx.x == 0) {
        int sum = 0;
        for (int b = 0; b < nblk; ++b) { blkofs[b] = sum; sum += blksum[b]; }
        row_ofs[N_NODES] = sum;
    }
}

__global__ void k_scan_local(const int* __restrict__ deg, const int* __restrict__ blkofs,
                             int* __restrict__ row_ofs, int* __restrict__ cursor) {
    __shared__ int sh[256];
    int i = blockIdx.x * 256 + threadIdx.x;
    int v = (i < N_NODES) ? deg[i] : 0;
    sh[threadIdx.x] = v;
    __syncthreads();
    for (int off = 1; off < 256; off <<= 1) {
        int t = (threadIdx.x >= off) ? sh[threadIdx.x - off] : 0;
        __syncthreads();
        sh[threadIdx.x] += t;
        __syncthreads();
    }
    if (i < N_NODES) {
        int ex = blkofs[blockIdx.x] + sh[threadIdx.x] - v;  // exclusive
        row_ofs[i] = ex;
        cursor[i] = ex;
    }
}

__global__ void k_scatter(const int* __restrict__ rows, const int* __restrict__ cols,
                          const float* __restrict__ vals, int* __restrict__ cursor,
                          int* __restrict__ cols_csr, float* __restrict__ vals_csr) {
    int e = blockIdx.x * 256 + threadIdx.x;
    if (e < N_EDGES) {
        int r = rows[e];
        int p = atomicAdd(&cursor[r], 1);
        cols_csr[p] = cols[e];
        vals_csr[p] = vals[e];
    }
}

// ---------------------------------------------------------------------------
// SpMM 1: S1[N,128] = spmm(A).  One wave per node, float2 per lane.
// ---------------------------------------------------------------------------
__global__ __launch_bounds__(256) void k_spmm1(const float* __restrict__ A,
                                               const int* __restrict__ row_ofs,
                                               const int* __restrict__ cols_csr,
                                               const float* __restrict__ vals_csr,
                                               float* __restrict__ S1) {
    int wave = threadIdx.x >> 6;
    int lane = threadIdx.x & 63;
    int node = blockIdx.x * 4 + wave;
    if (node >= N_NODES) return;
    int s = row_ofs[node], e = row_ofs[node + 1];
    const float2* A2 = (const float2*)A;
    float ax = 0.f, ay = 0.f;
    for (int t = s; t < e; ++t) {
        int c = cols_csr[t];
        float v = vals_csr[t];
        float2 xv = A2[(size_t)c * 64 + lane];
        ax += v * xv.x;
        ay += v * xv.y;
    }
    ((float2*)S1)[(size_t)node * 64 + lane] = make_float2(ax, ay);
}

// ---------------------------------------------------------------------------
// SpMM 2 + fused epilogue:
// out[i][j] = relu( spmm(S1[:, :64])[i][j] + r[i]*c2[j] + b2[j] )
//             + S1[i][64+j] + cr[j]
// ---------------------------------------------------------------------------
__global__ __launch_bounds__(256) void k_spmm2_out(const float* __restrict__ S1,
                                                   const int* __restrict__ row_ofs,
                                                   const int* __restrict__ cols_csr,
                                                   const float* __restrict__ vals_csr,
                                                   const float* __restrict__ c2,
                                                   const float* __restrict__ cr,
                                                   const float* __restrict__ b2,
                                                   float* __restrict__ out) {
    int wave = threadIdx.x >> 6;
    int lane = threadIdx.x & 63;
    int node = blockIdx.x * 4 + wave;
    if (node >= N_NODES) return;
    int s = row_ofs[node], e = row_ofs[node + 1];
    float acc = 0.f, rsum = 0.f;
    for (int t = s; t < e; ++t) {
        int c = cols_csr[t];
        float v = vals_csr[t];
        rsum += v;
        acc += v * S1[(size_t)c * FCAT + lane];
    }
    float o = acc + rsum * c2[lane] + b2[lane];
    float res = S1[(size_t)node * FCAT + NCLASS + lane] + cr[lane];
    out[(size_t)node * NCLASS + lane] = fmaxf(o, 0.f) + res;
}

// ---------------------------------------------------------------------------
extern "C" void kernel_launch(void* const* d_in, const int* in_sizes, int n_in,
                              void* d_out, int out_size, void* d_ws, size_t ws_size,
                              hipStream_t stream) {
    const float* x        = (const float*)d_in[0];
    const int*   adj_rows = (const int*)d_in[1];
    const int*   adj_cols = (const int*)d_in[2];
    const float* adj_vals = (const float*)d_in[3];
    const float* W1       = (const float*)d_in[4];
    const float* b1       = (const float*)d_in[5];
    const float* W2       = (const float*)d_in[6];
    const float* b2       = (const float*)d_in[7];
    const float* Wres     = (const float*)d_in[8];
    const float* bres     = (const float*)d_in[9];
    float* out = (float*)d_out;

    char* ws = (char*)d_ws;
    size_t off = 0;
    auto alloc = [&](size_t bytes) {
        size_t o = off;
        off += (bytes + 511) & ~511ULL;
        return o;
    };
    const int NBLK_SCAN = (N_NODES + 255) / 256;  // 391

    float* Wcat     = (float*)(ws + alloc((size_t)NFEAT * FCAT * 4));
    float* c2       = (float*)(ws + alloc(NCLASS * 4));
    float* cr       = (float*)(ws + alloc(NCLASS * 4));
    float* A        = (float*)(ws + alloc((size_t)N_NODES * FCAT * 4));
    float* S1       = (float*)(ws + alloc((size_t)N_NODES * FCAT * 4));
    int*   deg      = (int*)(ws + alloc((size_t)N_NODES * 4));
    int*   row_ofs  = (int*)(ws + alloc((size_t)(N_NODES + 1) * 4));
    int*   cursor   = (int*)(ws + alloc((size_t)N_NODES * 4));
    int*   blksum   = (int*)(ws + alloc((size_t)NBLK_SCAN * 4));
    int*   blkofs   = (int*)(ws + alloc((size_t)NBLK_SCAN * 4));
    int*   cols_csr = (int*)(ws + alloc((size_t)N_EDGES * 4));
    float* vals_csr = (float*)(ws + alloc((size_t)N_EDGES * 4));
    (void)ws_size; (void)in_sizes; (void)n_in; (void)out_size;

    // weight prep (tiny)
    k_prep_wcat<<<NFEAT, FCAT, 0, stream>>>(W1, W2, Wres, Wcat);
    k_prep_c<<<1, FCAT, 0, stream>>>(b1, W2, Wres, bres, c2, cr);

    // dense GEMM a = x @ Wcat
    k_gemm_a<<<(N_NODES + BM - 1) / BM, 256, 0, stream>>>(x, Wcat, A);

    // CSR build
    hipMemsetAsync(deg, 0, (size_t)N_NODES * 4, stream);
    k_hist<<<(N_EDGES + 255) / 256, 256, 0, stream>>>(adj_rows, deg);
    k_blocksums<<<NBLK_SCAN, 256, 0, stream>>>(deg, blksum);
    k_scan_blk<<<1, 64, 0, stream>>>(blksum, blkofs, NBLK_SCAN, row_ofs);
    k_scan_local<<<NBLK_SCAN, 256, 0, stream>>>(deg, blkofs, row_ofs, cursor);
    k_scatter<<<(N_EDGES + 255) / 256, 256, 0, stream>>>(adj_rows, adj_cols, adj_vals,
                                                         cursor, cols_csr, vals_csr);

    // spmm 1: S1 = spmm(A)
    k_spmm1<<<(N_NODES + 3) / 4, 256, 0, stream>>>(A, row_ofs, cols_csr, vals_csr, S1);

    // spmm 2 + epilogue
    k_spmm2_out<<<(N_NODES + 3) / 4, 256, 0, stream>>>(S1, row_ofs, cols_csr, vals_csr,
                                                       c2, cr, b2, out);
}

// Round 2
// 814.791 us; speedup vs baseline: 1.4310x; 1.4310x over previous
//
#include <hip/hip_runtime.h>

#define N_NODES 100000
#define N_EDGES 3200000
#define NFEAT 512
#define NHID 256
#define NCLASS 64
#define FCAT 128  // 2*NCLASS

typedef __attribute__((ext_vector_type(8))) short short8;
typedef __attribute__((ext_vector_type(4))) float f32x4;

static __device__ __forceinline__ unsigned short f2bf(float f) {
    unsigned u = __float_as_uint(f);
    unsigned r = (u + 0x7FFF + ((u >> 16) & 1)) >> 16;  // RNE
    return (unsigned short)r;
}
static __device__ __forceinline__ float bf2f(unsigned s) {
    return __uint_as_float(s << 16);
}

// ---------------------------------------------------------------------------
// Weight prep: WT[j][k] = Wcat[k][j] = sum_m W1[k][m] * (j<64 ? W2 : Wres)[m][j&63]
// stored bf16, N-major [FCAT][NFEAT] so MFMA B-fragments are k-contiguous.
// ---------------------------------------------------------------------------
__global__ void k_prep_wcat(const float* __restrict__ W1, const float* __restrict__ W2,
                            const float* __restrict__ Wres, unsigned short* __restrict__ WT) {
    int k = blockIdx.x;        // 0..511
    int j = threadIdx.x;       // 0..127
    const float* wb = (j < NCLASS) ? W2 : Wres;
    int jj = j & (NCLASS - 1);
    const float* w1row = W1 + (size_t)k * NHID;
    float acc = 0.f;
    for (int m = 0; m < NHID; ++m)
        acc += w1row[m] * wb[(size_t)m * NCLASS + jj];
    WT[(size_t)j * NFEAT + k] = f2bf(acc);
}

// c2[j] = b1 @ W2 ; cr[j] = b1 @ Wres + bres
__global__ void k_prep_c(const float* __restrict__ b1, const float* __restrict__ W2,
                         const float* __restrict__ Wres, const float* __restrict__ bres,
                         float* __restrict__ c2, float* __restrict__ cr) {
    int j = threadIdx.x;  // 0..127
    const float* wb = (j < NCLASS) ? W2 : Wres;
    int jj = j & (NCLASS - 1);
    float acc = 0.f;
    for (int m = 0; m < NHID; ++m)
        acc += b1[m] * wb[(size_t)m * NCLASS + jj];
    if (j < NCLASS) c2[jj] = acc;
    else            cr[jj] = acc + bres[jj];
}

// ---------------------------------------------------------------------------
// MFMA GEMM: A_bf16[N,128] = bf16(X[N,512] @ Wcat[512,128])
// block 256 = 4 waves; BM=128 (32 rows/wave), BN=128, BK=32.
// LDS tiles As[128][32], Bs[128][32] bf16, 16B-slot XOR swizzle (2-way max).
// ---------------------------------------------------------------------------
#define GBM 128
#define GBK 32
__global__ __launch_bounds__(256) void k_gemm_a(const float* __restrict__ X,
                                                const unsigned short* __restrict__ WT,
                                                unsigned short* __restrict__ A) {
    __shared__ __align__(16) short As[GBM * GBK];  // 8 KB
    __shared__ __align__(16) short Bs[FCAT * GBK]; // 8 KB
    int tid = threadIdx.x;
    int lane = tid & 63;
    int w = tid >> 6;
    int row0 = blockIdx.x * GBM;
    f32x4 acc[2][8] = {};

    for (int k0 = 0; k0 < NFEAT; k0 += GBK) {
        // stage X tile (f32 -> bf16): 128 rows x 32 k = 1024 float4, 4/thread
#pragma unroll
        for (int q = 0; q < 4; ++q) {
            int s = tid + q * 256;
            int r = s >> 3, c = s & 7;          // c: 4-float chunk (8B bf16)
            int gr = row0 + r;
            float4 v = make_float4(0.f, 0.f, 0.f, 0.f);
            if (gr < N_NODES)
                v = *(const float4*)(X + (size_t)gr * NFEAT + k0 + c * 4);
            int c8 = c >> 1;
            int c8s = c8 ^ ((r >> 1) & 3);
            ushort4 pv = make_ushort4(f2bf(v.x), f2bf(v.y), f2bf(v.z), f2bf(v.w));
            *(ushort4*)((unsigned short*)As + r * GBK + c8s * 8 + (c & 1) * 4) = pv;
        }
        // stage WT tile (bf16): 128 n x 32 k = 512 x 16B, 2/thread
#pragma unroll
        for (int q = 0; q < 2; ++q) {
            int s = tid + q * 256;
            int n = s >> 2, c8 = s & 3;
            int c8s = c8 ^ ((n >> 1) & 3);
            *(uint4*)((unsigned short*)Bs + n * GBK + c8s * 8) =
                *(const uint4*)(WT + (size_t)n * NFEAT + k0 + c8 * 8);
        }
        __syncthreads();

        int lr = lane & 15, ls = lane >> 4;
        short8 af[2];
#pragma unroll
        for (int mf = 0; mf < 2; ++mf) {
            int r = w * 32 + mf * 16 + lr;
            int ss = ls ^ ((r >> 1) & 3);
            af[mf] = *(short8*)(As + r * GBK + ss * 8);
        }
#pragma unroll
        for (int nf = 0; nf < 8; ++nf) {
            int n = nf * 16 + lr;
            int ss = ls ^ ((n >> 1) & 3);
            short8 bfr = *(short8*)(Bs + n * GBK + ss * 8);
            acc[0][nf] = __builtin_amdgcn_mfma_f32_16x16x32_bf16(af[0], bfr, acc[0][nf], 0, 0, 0);
            acc[1][nf] = __builtin_amdgcn_mfma_f32_16x16x32_bf16(af[1], bfr, acc[1][nf], 0, 0, 0);
        }
        __syncthreads();
    }

    // epilogue: C/D layout col=lane&15, row=(lane>>4)*4+j
    int lr = lane & 15, lq = lane >> 4;
#pragma unroll
    for (int mf = 0; mf < 2; ++mf) {
#pragma unroll
        for (int j = 0; j < 4; ++j) {
            int gr = row0 + w * 32 + mf * 16 + lq * 4 + j;
            if (gr < N_NODES) {
#pragma unroll
                for (int nf = 0; nf < 8; ++nf)
                    A[(size_t)gr * FCAT + nf * 16 + lr] = f2bf(acc[mf][nf][j]);
            }
        }
    }
}

// ---------------------------------------------------------------------------
// CSR build (packed {col, val} int2 edges)
// ---------------------------------------------------------------------------
__global__ void k_hist(const int* __restrict__ rows, int* __restrict__ deg) {
    int e = blockIdx.x * 256 + threadIdx.x;
    if (e < N_EDGES) atomicAdd(&deg[rows[e]], 1);
}

__global__ void k_blocksums(const int* __restrict__ deg, int* __restrict__ blksum) {
    __shared__ int sh[256];
    int i = blockIdx.x * 256 + threadIdx.x;
    sh[threadIdx.x] = (i < N_NODES) ? deg[i] : 0;
    __syncthreads();
    for (int off = 128; off > 0; off >>= 1) {
        if (threadIdx.x < off) sh[threadIdx.x] += sh[threadIdx.x + off];
        __syncthreads();
    }
    if (threadIdx.x == 0) blksum[blockIdx.x] = sh[0];
}

__global__ void k_scan_blk(const int* __restrict__ blksum, int* __restrict__ blkofs,
                           int nblk, int* __restrict__ row_ofs) {
    if (threadIdx.x == 0 && blockIdx.x == 0) {
        int sum = 0;
        for (int b = 0; b < nblk; ++b) { blkofs[b] = sum; sum += blksum[b]; }
        row_ofs[N_NODES] = sum;
    }
}

__global__ void k_scan_local(const int* __restrict__ deg, const int* __restrict__ blkofs,
                             int* __restrict__ row_ofs, int* __restrict__ cursor) {
    __shared__ int sh[256];
    int i = blockIdx.x * 256 + threadIdx.x;
    int v = (i < N_NODES) ? deg[i] : 0;
    sh[threadIdx.x] = v;
    __syncthreads();
    for (int off = 1; off < 256; off <<= 1) {
        int t = (threadIdx.x >= off) ? sh[threadIdx.x - off] : 0;
        __syncthreads();
        sh[threadIdx.x] += t;
        __syncthreads();
    }
    if (i < N_NODES) {
        int ex = blkofs[blockIdx.x] + sh[threadIdx.x] - v;  // exclusive
        row_ofs[i] = ex;
        cursor[i] = ex;
    }
}

__global__ void k_scatter(const int* __restrict__ rows, const int* __restrict__ cols,
                          const float* __restrict__ vals, int* __restrict__ cursor,
                          int2* __restrict__ csr) {
    int e = blockIdx.x * 256 + threadIdx.x;
    if (e < N_EDGES) {
        int r = rows[e];
        int p = atomicAdd(&cursor[r], 1);
        csr[p] = make_int2(cols[e], __float_as_int(vals[e]));
    }
}

// ---------------------------------------------------------------------------
// SpMM 1: gathers bf16 A rows (256 B/edge). Lane l owns cols {2l, 2l+1}.
// cols 0..63  -> S1a bf16 (packed uint), gathered again by spmm2
// cols 64..127-> S1r f32 (residual, streamed once)
// ---------------------------------------------------------------------------
__global__ __launch_bounds__(256) void k_spmm1(const unsigned* __restrict__ A32,
                                               const int* __restrict__ row_ofs,
                                               const int2* __restrict__ csr,
                                               unsigned* __restrict__ S1a,
                                               float2* __restrict__ S1r) {
    int wv = threadIdx.x >> 6, lane = threadIdx.x & 63;
    int node = blockIdx.x * 4 + wv;
    if (node >= N_NODES) return;
    int s = row_ofs[node], e = row_ofs[node + 1];
    float a0 = 0.f, a1 = 0.f;
    int t = s;
    for (; t + 1 < e; t += 2) {
        int2 cv0 = csr[t], cv1 = csr[t + 1];
        unsigned p0 = A32[cv0.x * 64 + lane];
        unsigned p1 = A32[cv1.x * 64 + lane];
        float v0 = __int_as_float(cv0.y), v1 = __int_as_float(cv1.y);
        a0 += v0 * bf2f(p0 & 0xffffu) + v1 * bf2f(p1 & 0xffffu);
        a1 += v0 * bf2f(p0 >> 16) + v1 * bf2f(p1 >> 16);
    }
    if (t < e) {
        int2 cv = csr[t];
        unsigned p = A32[cv.x * 64 + lane];
        float v = __int_as_float(cv.y);
        a0 += v * bf2f(p & 0xffffu);
        a1 += v * bf2f(p >> 16);
    }
    if (lane < 32)
        S1a[node * 32 + lane] = (unsigned)f2bf(a0) | ((unsigned)f2bf(a1) << 16);
    else
        S1r[node * 32 + (lane - 32)] = make_float2(a0, a1);
}

// ---------------------------------------------------------------------------
// SpMM 2 + fused epilogue (gathers bf16 S1a rows, 128 B/edge):
// out[i][j] = relu(spmm(S1a)[i][j] + r[i]*c2[j] + b2[j]) + S1r[i][j] + cr[j]
// ---------------------------------------------------------------------------
__global__ __launch_bounds__(256) void k_spmm2_out(const unsigned short* __restrict__ S1a16,
                                                   const float* __restrict__ S1r,
                                                   const int* __restrict__ row_ofs,
                                                   const int2* __restrict__ csr,
                                                   const float* __restrict__ c2,
                                                   const float* __restrict__ cr,
                                                   const float* __restrict__ b2,
                                                   float* __restrict__ out) {
    int wv = threadIdx.x >> 6, lane = threadIdx.x & 63;
    int node = blockIdx.x * 4 + wv;
    if (node >= N_NODES) return;
    int s = row_ofs[node], e = row_ofs[node + 1];
    float acc = 0.f, rsum = 0.f;
    int t = s;
    for (; t + 1 < e; t += 2) {
        int2 cv0 = csr[t], cv1 = csr[t + 1];
        float v0 = __int_as_float(cv0.y), v1 = __int_as_float(cv1.y);
        rsum += v0 + v1;
        acc += v0 * bf2f((unsigned)S1a16[cv0.x * 64 + lane])
             + v1 * bf2f((unsigned)S1a16[cv1.x * 64 + lane]);
    }
    if (t < e) {
        int2 cv = csr[t];
        float v = __int_as_float(cv.y);
        rsum += v;
        acc += v * bf2f((unsigned)S1a16[cv.x * 64 + lane]);
    }
    float o = acc + rsum * c2[lane] + b2[lane];
    float res = S1r[node * 64 + lane] + cr[lane];
    out[node * 64 + lane] = fmaxf(o, 0.f) + res;
}

// ---------------------------------------------------------------------------
extern "C" void kernel_launch(void* const* d_in, const int* in_sizes, int n_in,
                              void* d_out, int out_size, void* d_ws, size_t ws_size,
                              hipStream_t stream) {
    const float* x        = (const float*)d_in[0];
    const int*   adj_rows = (const int*)d_in[1];
    const int*   adj_cols = (const int*)d_in[2];
    const float* adj_vals = (const float*)d_in[3];
    const float* W1       = (const float*)d_in[4];
    const float* b1       = (const float*)d_in[5];
    const float* W2       = (const float*)d_in[6];
    const float* b2       = (const float*)d_in[7];
    const float* Wres     = (const float*)d_in[8];
    const float* bres     = (const float*)d_in[9];
    float* out = (float*)d_out;

    char* ws = (char*)d_ws;
    size_t off = 0;
    auto alloc = [&](size_t bytes) {
        size_t o = off;
        off += (bytes + 511) & ~511ULL;
        return o;
    };
    const int NBLK_SCAN = (N_NODES + 255) / 256;  // 391

    unsigned short* WT  = (unsigned short*)(ws + alloc((size_t)NFEAT * FCAT * 2));
    float* c2           = (float*)(ws + alloc(NCLASS * 4));
    float* cr           = (float*)(ws + alloc(NCLASS * 4));
    unsigned short* A   = (unsigned short*)(ws + alloc((size_t)N_NODES * FCAT * 2));
    unsigned* S1a       = (unsigned*)(ws + alloc((size_t)N_NODES * 32 * 4));
    float* S1r          = (float*)(ws + alloc((size_t)N_NODES * 64 * 4));
    int*   deg      = (int*)(ws + alloc((size_t)N_NODES * 4));
    int*   row_ofs  = (int*)(ws + alloc((size_t)(N_NODES + 1) * 4));
    int*   cursor   = (int*)(ws + alloc((size_t)N_NODES * 4));
    int*   blksum   = (int*)(ws + alloc((size_t)NBLK_SCAN * 4));
    int*   blkofs   = (int*)(ws + alloc((size_t)NBLK_SCAN * 4));
    int2*  csr      = (int2*)(ws + alloc((size_t)N_EDGES * 8));
    (void)ws_size; (void)in_sizes; (void)n_in; (void)out_size;

    // weight prep (tiny)
    k_prep_wcat<<<NFEAT, FCAT, 0, stream>>>(W1, W2, Wres, WT);
    k_prep_c<<<1, FCAT, 0, stream>>>(b1, W2, Wres, bres, c2, cr);

    // dense MFMA GEMM: A = bf16(x @ Wcat)
    k_gemm_a<<<(N_NODES + GBM - 1) / GBM, 256, 0, stream>>>(x, WT, A);

    // CSR build
    hipMemsetAsync(deg, 0, (size_t)N_NODES * 4, stream);
    k_hist<<<(N_EDGES + 255) / 256, 256, 0, stream>>>(adj_rows, deg);
    k_blocksums<<<NBLK_SCAN, 256, 0, stream>>>(deg, blksum);
    k_scan_blk<<<1, 64, 0, stream>>>(blksum, blkofs, NBLK_SCAN, row_ofs);
    k_scan_local<<<NBLK_SCAN, 256, 0, stream>>>(deg, blkofs, row_ofs, cursor);
    k_scatter<<<(N_EDGES + 255) / 256, 256, 0, stream>>>(adj_rows, adj_cols, adj_vals,
                                                         cursor, csr);

    // spmm 1: S1 = spmm(A)  (bf16 gather)
    k_spmm1<<<(N_NODES + 3) / 4, 256, 0, stream>>>((const unsigned*)A, row_ofs, csr,
                                                   S1a, (float2*)S1r);

    // spmm 2 + epilogue
    k_spmm2_out<<<(N_NODES + 3) / 4, 256, 0, stream>>>((const unsigned short*)S1a, S1r,
                                                       row_ofs, csr, c2, cr, b2, out);
}